// Round 9
// baseline (230.068 us; speedup 1.0000x reference)
//
#include <hip/hip_runtime.h>
#include <hip/hip_bf16.h>

typedef unsigned short ushort_t;
typedef __attribute__((ext_vector_type(8))) short short8;
typedef __attribute__((ext_vector_type(4))) float floatx4;

#define G_   129
#define F_   96
#define O_   96
#define OT   48     // per-block O-tile (O split across 2 blocks)
#define T_   512
#define KD   288    // K*F, kd = kk*96 + f
#define LDB  296    // Wl padded row stride (288 + 8)
#define SROW 40     // x-slab row stride in ushorts (80 B) -> bank-conflict-free
#define SLAB (36 * SROW)   // per-wave slab: 36 rows (34 used) = 2880 B

// f32 -> bf16 RNE (finite inputs)
__device__ __forceinline__ unsigned f2bf(float f) {
    unsigned u = __builtin_bit_cast(unsigned, f);
    u += 0x7FFFu + ((u >> 16) & 1u);
    return u >> 16;
}
// packed pair f32x2 -> bf16x2 in one dword (integer ops only)
__device__ __forceinline__ unsigned pk2(float a, float b) {
    return f2bf(a) | (f2bf(b) << 16);
}

// Separate permute (r8 fusion regressed: it put 8x-redundant w reads on every
// block's critical path). w (f32, [G,O,F,K]) -> wt (bf16, [G,O,kd]), kd=kk*96+f.
__global__ void wt_permute(const float* __restrict__ w, ushort_t* __restrict__ wt) {
    int i = blockIdx.x * 256 + threadIdx.x;
    const int total = G_ * O_ * KD;
    if (i >= total) return;
    int base = i / KD;
    int kd = i - base * KD;
    int kk = kd / F_;
    int f  = kd - kk * F_;
    wt[i] = (ushort_t)f2bf(w[base * KD + f * 3 + kk]);
}

// 512 thr = 8 waves, M-tile 256, O-tile 48 (blockIdx.x&1 picks the half).
// LDS: Wl 28.4KB + Xs 23KB = 51.5KB -> 3 blocks/CU = 24 waves/CU.
// x staged per-WAVE (private slab, no barrier), each row read once, reused by
// all 3 taps; depth-1 f-block register prefetch. One barrier total.
__global__ __launch_bounds__(512, 6) void conv_mfma(
    const float* __restrict__ x, const ushort_t* __restrict__ wt,
    const float* __restrict__ bias, float* __restrict__ out)
{
    __shared__ __align__(16) ushort_t Wl[OT * LDB];   // 28,416 B
    __shared__ __align__(16) ushort_t Xs[8 * SLAB];   // 23,040 B

    const int g    = blockIdx.y;
    const int bx   = blockIdx.x;
    const int m0   = (bx >> 1) * 256;
    const int o0   = (bx & 1) * OT;
    const int tid  = threadIdx.x;
    const int wave = tid >> 6;
    const int lane = tid & 63;
    const int ln   = lane & 15;
    const int q    = lane >> 4;

    // Stage this block's weight half: 48 rows x 288 bf16 (stride 296)
    {
        const ushort_t* src = wt + ((size_t)g * O_ + o0) * KD;
        for (int idx = tid; idx < OT * 36; idx += 512) {
            int o = idx / 36;
            int s = idx - o * 36;
            *(short8*)&Wl[o * LDB + s * 8] = *(const short8*)&src[o * KD + s * 8];
        }
    }
    __syncthreads();   // the only barrier

    const int m0r = m0 + wave * 32;       // this wave's 32 rows
    const int b   = m0r >> 9;
    const int tb  = m0r & 511;

    // Slab staging constants: 5 insts x 64 lanes; slab row rr = global t tb+rr-1.
    const float* tp[5];
    int  laddr[5];
    bool wr[5], vld[5];
    #pragma unroll
    for (int i = 0; i < 5; ++i) {
        int task = i * 64 + lane;
        int row = task >> 3;            // 0..39
        int seg = task & 7;             // 8 segs x 4 floats = one 32-f block
        int tl = tb + row - 1;
        wr[i]  = row < 34;
        vld[i] = wr[i] && ((unsigned)tl < (unsigned)T_);
        int tc = tl < 0 ? 0 : (tl > T_ - 1 ? T_ - 1 : tl);
        tp[i] = x + ((size_t)((b * T_ + tc) * G_ + g) * F_ + seg * 4);
        laddr[i] = wave * SLAB + row * SROW + seg * 4;
    }

    auto issueX = [&](int fb, floatx4* v) {
        #pragma unroll
        for (int i = 0; i < 5; ++i)
            v[i] = *(const floatx4*)(tp[i] + fb * 32);
    };
    auto writeX = [&](const floatx4* v) {
        #pragma unroll
        for (int i = 0; i < 5; ++i) {
            if (wr[i]) {
                unsigned lo = pk2(v[i][0], v[i][1]);
                unsigned hi = pk2(v[i][2], v[i][3]);
                if (!vld[i]) { lo = 0u; hi = 0u; }
                uint2 d; d.x = lo; d.y = hi;
                *(uint2*)&Xs[laddr[i]] = d;
            }
        }
    };

    floatx4 acc[2][3];
    #pragma unroll
    for (int s = 0; s < 2; ++s)
        #pragma unroll
        for (int nt = 0; nt < 3; ++nt)
            acc[s][nt] = (floatx4){0.f, 0.f, 0.f, 0.f};

    floatx4 cur[5], nxt[5];
    issueX(0, cur);

    #pragma unroll
    for (int fb = 0; fb < 3; ++fb) {
        if (fb < 2) issueX(fb + 1, nxt);   // keep next f-block's 5 loads in flight
        writeX(cur);                        // waits only on cur's loads

        #pragma unroll
        for (int kk = 0; kk < 3; ++kk) {
            const short8 a0 = *(const short8*)&Xs[wave * SLAB + (ln + kk) * SROW + q * 8];
            const short8 a1 = *(const short8*)&Xs[wave * SLAB + (16 + ln + kk) * SROW + q * 8];
            const int c32 = (kk * 3 + fb) * 32;   // Wl column block kd = kk*96 + fb*32
            #pragma unroll
            for (int nt = 0; nt < 3; ++nt) {
                const short8 bb = *(const short8*)&Wl[(nt * 16 + ln) * LDB + c32 + q * 8];
                acc[0][nt] = __builtin_amdgcn_mfma_f32_16x16x32_bf16(a0, bb, acc[0][nt], 0, 0, 0);
                acc[1][nt] = __builtin_amdgcn_mfma_f32_16x16x32_bf16(a1, bb, acc[1][nt], 0, 0, 0);
            }
        }
        #pragma unroll
        for (int i = 0; i < 5; ++i) cur[i] = nxt[i];
    }

    // Epilogue: D row = q*4 + reg, col = ln; + bias; f32 out.
    #pragma unroll
    for (int s = 0; s < 2; ++s) {
        int mbase = m0 + wave * 32 + s * 16 + q * 4;
        #pragma unroll
        for (int nt = 0; nt < 3; ++nt) {
            int o = o0 + nt * 16 + ln;
            float bv = bias[g * O_ + o];
            #pragma unroll
            for (int r = 0; r < 4; ++r) {
                int m = mbase + r;
                out[(size_t)(m * G_ + g) * O_ + o] = acc[s][nt][r] + bv;
            }
        }
    }
}

extern "C" void kernel_launch(void* const* d_in, const int* in_sizes, int n_in,
                              void* d_out, int out_size, void* d_ws, size_t ws_size,
                              hipStream_t stream) {
    const float* x    = (const float*)d_in[0];
    const float* w    = (const float*)d_in[1];
    const float* bias = (const float*)d_in[2];
    float* out = (float*)d_out;
    ushort_t* wt = (ushort_t*)d_ws;   // 129*96*288*2 = 7,133,184 B

    const int total_w = G_ * O_ * KD;
    wt_permute<<<dim3((total_w + 255) / 256), dim3(256), 0, stream>>>(w, wt);

    dim3 grid(16, G_);   // x = mtile*2 + o-half (adjacent pairs share x for L2/L3)
    conv_mfma<<<grid, dim3(512), 0, stream>>>(x, wt, bias, out);
}